// Round 11
// baseline (79.375 us; speedup 1.0000x reference)
//
#include <hip/hip_runtime.h>
#include <math.h>

// DecoderGATLayer — 2 flat kernels. f32. S=192, B=2, E=512, H=2, D=256, BH=4.
// Dead inputs: ex_entity, ex_relation, Wxe, Wxr (reference deletes `we`).
// score[bh,t,s] = A[s&3][i] + B[t&3][s] + C[s&3][i] - C[s&3][j] + ba,
//   i = bh*48 + (t>>2), j = (t&3)*48 + (s>>2)
// q/k projections folded into tables via u = W^T wa_slice (verified r7).
// NEW: PV in INPUT space (sum p = 1):
//   attn_out(t,b)[h*256+d] = (W_h @ y_{h,t,b})[d] + bias_h[d],
//   y_{h,t,b} = sum_s p_h[s] * X_h[s,b,:],  X_0 = query, X_1 = entity.
// Then out = attn_out @ Wo^T + bo. All heavy streams read pristine inputs.

#define SS 192
// ws float offsets
#define WTV 0          // [128 k4][256 d] float4-over-k  (131072 floats)
#define WTE 131072
#define WTO 262144     // [128 k4][512 c] float4-over-k  (262144 floats)
#define TO  524288     // 12*192 score tables
// end 526592 floats = 2.1 MB

__device__ __forceinline__ float wave_reduce_add(float p) {
    #pragma unroll
    for (int off = 32; off >= 1; off >>= 1) p += __shfl_xor(p, off, 64);
    return p;
}

// ===== K1: transposes (blk 0..127) + A/B tables (128..135) + C tables (136..139)
// (round-9 k_prep verbatim, new offsets)
__global__ __launch_bounds__(1024) void k_prep(
    const float* __restrict__ query, const float* __restrict__ entity,
    const float* __restrict__ Wq, const float* __restrict__ bq,
    const float* __restrict__ Wk, const float* __restrict__ bk,
    const float* __restrict__ Wv, const float* __restrict__ We,
    const float* __restrict__ be, const float* __restrict__ Wa,
    const float* __restrict__ Wo, float* __restrict__ ws)
{
    __shared__ __align__(16) float red[16 * 512];   // 32 KB
    __shared__ __align__(16) float uo[516];
    int blk = blockIdx.x;
    int tid = threadIdx.x;

    if (blk < 128) {
        // WT4[k4*D + d] = W4[d*128 + k4]; coalesced read, scattered write
        int o = blk * 1024 + tid;              // 0..131071
        const float4* src; float4* dst; int idx; int D;
        if (o < 32768)      { src = (const float4*)Wv; dst = (float4*)(ws + WTV); idx = o;         D = 256; }
        else if (o < 65536) { src = (const float4*)We; dst = (float4*)(ws + WTE); idx = o - 32768; D = 256; }
        else                { src = (const float4*)Wo; dst = (float4*)(ws + WTO); idx = o - 65536; D = 512; }
        int d  = idx >> 7;
        int k4 = idx & 127;
        dst[k4 * D + d] = src[idx];
        return;
    }

    int wv   = __builtin_amdgcn_readfirstlane(tid >> 6);
    int lane = tid & 63;

    if (blk < 136) {
        // A/B tables via u = W^T wa_slice (verified r7 body)
        int tab = blk - 128;                   // 0..7
        int p   = (tab < 4) ? tab : tab - 4;
        int b   = p >> 1, h = p & 1;
        const float* wa   = Wa + ((tab < 4) ? 0 : 256);
        const float* W    = h ? We : ((tab < 4) ? Wq : Wk);
        const float* bias = h ? be : ((tab < 4) ? bq : bk);
        const float* x    = h ? entity : query;

        float u8[8];
        #pragma unroll
        for (int i = 0; i < 8; i++) u8[i] = 0.f;
        #pragma unroll 4
        for (int dd = 0; dd < 16; dd++) {
            int d = wv * 16 + dd;
            float wad = wa[d];                                  // wave-uniform
            const float4* Wr = (const float4*)(W + (size_t)d * 512);
            float4 w0 = Wr[lane * 2], w1 = Wr[lane * 2 + 1];    // coalesced
            u8[0] += wad * w0.x; u8[1] += wad * w0.y; u8[2] += wad * w0.z; u8[3] += wad * w0.w;
            u8[4] += wad * w1.x; u8[5] += wad * w1.y; u8[6] += wad * w1.z; u8[7] += wad * w1.w;
        }
        #pragma unroll
        for (int i = 0; i < 8; i++) red[wv * 512 + lane * 8 + i] = u8[i];
        __syncthreads();
        if (tid < 512) {
            float s = 0.f;
            #pragma unroll
            for (int w = 0; w < 16; w++) s += red[w * 512 + tid];
            uo[tid] = s;
        }
        __syncthreads();
        if (tid < 256) red[tid] = wa[tid] * bias[tid];
        __syncthreads();
        for (int o = 128; o >= 1; o >>= 1) {
            if (tid < o) red[tid] += red[tid + o];
            __syncthreads();
        }
        float off = red[0];

        const float4* u4 = (const float4*)uo;
        float4 ua = u4[lane * 2], ub = u4[lane * 2 + 1];
        for (int rr = 0; rr < 12; rr++) {
            int r = wv * 12 + rr;
            const float4* xr = (const float4*)(x + (size_t)(r * 2 + b) * 512);
            float4 a0 = xr[lane * 2], a1 = xr[lane * 2 + 1];
            float pp = a0.x*ua.x + a0.y*ua.y + a0.z*ua.z + a0.w*ua.w
                     + a1.x*ub.x + a1.y*ub.y + a1.z*ub.z + a1.w*ub.w;
            pp = wave_reduce_add(pp);
            if (lane == 0) ws[TO + tab * SS + r] = pp + off;
        }
        return;
    }

    // C tables: C[m][i] = Wa[512:768) . entity[i*2+(m>>1)][(m&1)*256 ..]
    {
        int m = blk - 136;                     // 0..3
        float4 wa4 = ((const float4*)(Wa + 512))[lane];
        for (int rr = 0; rr < 12; rr++) {
            int i = wv * 12 + rr;
            const float4* er = (const float4*)(entity
                + (size_t)(i * 2 + (m >> 1)) * 512 + (m & 1) * 256);
            float4 e4 = er[lane];
            float pp = e4.x*wa4.x + e4.y*wa4.y + e4.z*wa4.z + e4.w*wa4.w;
            pp = wave_reduce_add(pp);
            if (lane == 0) ws[TO + (8 + m) * SS + i] = pp;
        }
    }
}

// ===== K2: softmax + input-space PV + W_h GEMV + Wo GEMV. 192 blocks x 1024 thr.
// block = (b, tg, half); handles t = tg*4 + half*2 + {0,1}, both heads, all 512 cols.
__global__ __launch_bounds__(1024) void k_main(
    const float* __restrict__ query, const float* __restrict__ entity,
    const float* __restrict__ bv, const float* __restrict__ be,
    const float* __restrict__ ba_p, const float* __restrict__ bo,
    const float* __restrict__ ws, float* __restrict__ out)
{
    __shared__ __align__(16) float spT[SS * 4];     // [s][h*2+tl]   3 KB
    __shared__ __align__(16) float part[4096];      // 16 KB multi-use
    __shared__ __align__(16) float y[2][2][512];    // [m][tl][k]    8 KB
    __shared__ __align__(16) float rows2[2][512];   // [tl][c']      4 KB
    int blk  = blockIdx.x;            // 0..191
    int b    = blk / 96;
    int rem  = blk % 96;
    int tg   = rem >> 1;              // 0..47
    int half = rem & 1;               // ti = half*2 + tl
    int tid  = threadIdx.x;
    int wvi  = __builtin_amdgcn_readfirstlane(tid >> 6);
    int lane = tid & 63;
    const float* T = ws + TO;
    float ba = ba_p[0];

    // --- softmax: waves 0..3 own (h = wvi>>1, tl = wvi&1)   [verified body]
    if (wvi < 4) {
        int h = wvi >> 1, tl = wvi & 1;
        int ti = half * 2 + tl;
        int bh = 2 * b + h;
        int i_idx = bh * 48 + tg;           // t>>2 == tg
        int tmod  = ti;                     // t&3 == ti
        float sc[3]; float mx = -1e30f;
        #pragma unroll
        for (int i = 0; i < 3; i++) {
            int s_ = lane + 64 * i;
            int m  = s_ & 3;
            int j  = tmod * 48 + (s_ >> 2);
            float xv = T[m * SS + i_idx] + T[(4 + tmod) * SS + s_]
                     + T[(8 + m) * SS + i_idx] - T[(8 + m) * SS + j] + ba;
            xv = (xv >= 0.f) ? xv : 0.01f * xv;      // leaky_relu
            sc[i] = xv; mx = fmaxf(mx, xv);
        }
        #pragma unroll
        for (int o = 32; o >= 1; o >>= 1) mx = fmaxf(mx, __shfl_xor(mx, o, 64));
        float sum = 0.f;
        #pragma unroll
        for (int i = 0; i < 3; i++) { sc[i] = __expf(sc[i] - mx); sum += sc[i]; }
        sum = wave_reduce_add(sum);
        float inv = 1.f / sum;
        #pragma unroll
        for (int i = 0; i < 3; i++)
            spT[(lane + 64 * i) * 4 + h * 2 + tl] = sc[i] * inv;
    }
    __syncthreads();

    // --- PV (input space): thread (m = tid>>9, sq = (tid>>8)&1, c2 = tid&255)
    // y[m][tl][:] = sum_s spT[s][m*2+tl] * X_m[s,b,:]
    {
        int m  = __builtin_amdgcn_readfirstlane(tid >> 9);
        int sq = __builtin_amdgcn_readfirstlane((tid >> 8) & 1);
        int c2 = tid & 255;                       // float2 column
        const float2* X2 = (const float2*)(m ? entity : query);
        const float4* spT4 = (const float4*)spT;
        float2 a0 = make_float2(0.f, 0.f), a1 = make_float2(0.f, 0.f);
        int s0 = sq * 96;
        #pragma unroll 8
        for (int s2 = 0; s2 < 96; s2++) {
            int s = s0 + s2;
            float4 p4 = spT4[s];                  // b128 broadcast: all 4 weights
            float2 v  = X2[(size_t)(s * 2 + b) * 256 + c2];
            float pa = m ? p4.z : p4.x;           // (h=m, tl=0)
            float pb = m ? p4.w : p4.y;           // (h=m, tl=1)
            a0.x += pa * v.x; a0.y += pa * v.y;
            a1.x += pb * v.x; a1.y += pb * v.y;
        }
        float2* pf2 = (float2*)part;              // [m*2+sq][tl][256 f2]
        int g = m * 2 + sq;
        pf2[g * 512 + c2]       = a0;
        pf2[g * 512 + 256 + c2] = a1;
    }
    __syncthreads();
    // reduce partials -> y (2048 floats, 2 per thread)
    #pragma unroll
    for (int o = 0; o < 2; o++) {
        int idx = o * 1024 + tid;                 // m*1024 + tl*512 + k
        int m   = idx >> 10;
        int rem1 = idx & 1023;
        ((float*)y)[idx] = part[(m * 2) * 1024 + rem1] + part[(m * 2 + 1) * 1024 + rem1];
    }
    __syncthreads();

    // --- stage1 GEMV: rows2[tl][m*256+d] = W_m @ y[m][tl] + bias_m
    // thread (m = tid>>9, kc = (tid>>7)&3, tl = (tid>>6)&1, lane): d = lane*4..+3
    {
        int m  = __builtin_amdgcn_readfirstlane(tid >> 9);
        int kc = __builtin_amdgcn_readfirstlane((tid >> 7) & 3);
        int tl = __builtin_amdgcn_readfirstlane((tid >> 6) & 1);
        int d0 = lane * 4;
        const float4* WT4 = (const float4*)(ws + (m ? WTE : WTV));  // [k4][256]
        const float4* y4  = (const float4*)&y[m][tl][0];
        float acc[4] = {0.f, 0.f, 0.f, 0.f};
        int k4b = kc * 32;
        #pragma unroll 8
        for (int i = 0; i < 32; i++) {
            int k4 = k4b + i;
            float4 a = y4[k4];                    // b128 broadcast
            #pragma unroll
            for (int j = 0; j < 4; j++) {
                float4 w = WT4[k4 * 256 + d0 + j];    // 64B/lane coalesced
                acc[j] += a.x * w.x + a.y * w.y + a.z * w.z + a.w * w.w;
            }
        }
        #pragma unroll
        for (int j = 0; j < 4; j++)
            part[kc * 1024 + tl * 512 + m * 256 + d0 + j] = acc[j];
    }
    __syncthreads();
    // reduce + bias -> rows2 (1024 outputs, 1 per thread); waves are bias-uniform
    {
        int cp = tid & 511;                       // c' = m*256+d
        float v = part[tid] + part[1024 + tid] + part[2048 + tid] + part[3072 + tid];
        float bias = (cp < 256) ? bv[cp] : be[cp - 256];
        rows2[tid >> 9][cp] = v + bias;
    }
    __syncthreads();

    // --- stage2 GEMV: out_row[c] = Wo @ rows2[tl] + bo
    // thread (kc = tid>>9, tl = (tid>>8)&1, cl = tid&255): cols c = 2*cl, 2*cl+1
    {
        int kc = __builtin_amdgcn_readfirstlane(tid >> 9);
        int tl = __builtin_amdgcn_readfirstlane((tid >> 8) & 1);
        int cl = tid & 255;
        int c0 = cl * 2;
        const float4* WTO4 = (const float4*)(ws + WTO);   // [k4][512]
        const float4* r4   = (const float4*)&rows2[tl][0];
        float acc0 = 0.f, acc1 = 0.f;
        int k4b = kc * 64;
        #pragma unroll 8
        for (int i = 0; i < 64; i++) {
            int k4 = k4b + i;
            float4 a  = r4[k4];                   // b128 broadcast
            float4 w0 = WTO4[k4 * 512 + c0];      // 32B/lane coalesced
            float4 w1 = WTO4[k4 * 512 + c0 + 1];
            acc0 += a.x * w0.x + a.y * w0.y + a.z * w0.z + a.w * w0.w;
            acc1 += a.x * w1.x + a.y * w1.y + a.z * w1.z + a.w * w1.w;
        }
        ((float2*)part)[kc * 512 + tl * 256 + cl] = make_float2(acc0, acc1);
    }
    __syncthreads();
    // final reduce + store (1024 outputs, 1 per thread, coalesced)
    {
        int tl = tid >> 9, c = tid & 511;
        float v = part[tid] + part[1024 + tid];
        int t = tg * 4 + half * 2 + tl;
        out[(size_t)(2 * t + b) * 512 + c] = v + bo[c];
    }
}

extern "C" void kernel_launch(void* const* d_in, const int* in_sizes, int n_in,
                              void* d_out, int out_size, void* d_ws, size_t ws_size,
                              hipStream_t stream) {
    const float* query  = (const float*)d_in[0];
    const float* entity = (const float*)d_in[1];
    // d_in[2] ex_entity, d_in[3] ex_relation: dead
    const float* Wq = (const float*)d_in[4];  const float* bq = (const float*)d_in[5];
    const float* Wk = (const float*)d_in[6];  const float* bk = (const float*)d_in[7];
    const float* Wv = (const float*)d_in[8];  const float* bv = (const float*)d_in[9];
    const float* We = (const float*)d_in[10]; const float* be = (const float*)d_in[11];
    // d_in[12..15] dead
    const float* Wa = (const float*)d_in[16]; const float* ba = (const float*)d_in[17];
    const float* Wo = (const float*)d_in[18]; const float* bo = (const float*)d_in[19];
    float* ws  = (float*)d_ws;
    float* out = (float*)d_out;

    hipLaunchKernelGGL(k_prep, dim3(140), dim3(1024), 0, stream,
                       query, entity, Wq, bq, Wk, bk, Wv, We, be, Wa, Wo, ws);
    hipLaunchKernelGGL(k_main, dim3(192), dim3(1024), 0, stream,
                       query, entity, bv, be, ba, bo, ws, out);
}

// Round 12
// 68.843 us; speedup vs baseline: 1.1530x; 1.1530x over previous
//
#include <hip/hip_runtime.h>
#include <math.h>

// DecoderGATLayer — 3 flat kernels. f32. S=192, B=2, E=512, H=2, D=256, BH=4.
// Dead inputs: ex_entity, ex_relation, Wxe, Wxr (reference deletes `we`).
// score[bh,t,s] = A[s&3][i] + B[t&3][s] + C[s&3][i] - C[s&3][j] + ba,
//   i = bh*48 + (t>>2), j = (t&3)*48 + (s>>2)
// q/k projections folded into tables via u = W^T wa_slice (verified r7).
// K1 prep: transposes Wv/We/Wo + tables.  K2: v,e projections (s_load rows).
// K3: attn (softmax + PV) + out GEMV; rows staged in ws so the GEMV reads
//     them via scalar-cache broadcasts; s_dcache_inv guards replay staleness.

#define SS 192
// ws float offsets
#define WTV 0          // [128 k4][256 d] float4-over-k
#define WTE 131072
#define WTO 262144     // [128 k4][512 c] float4-over-k
#define TO  524288     // 12*192 tables
#define VO  526592     // [384][256], row = s*2+b
#define EO  624896
#define ROWS 723200    // per-block rows: [96 blk][4 ti][512]
// end 919808 floats = 3.5 MB

__device__ __forceinline__ float wave_reduce_add(float p) {
    #pragma unroll
    for (int off = 32; off >= 1; off >>= 1) p += __shfl_xor(p, off, 64);
    return p;
}

// ===== K1: transposes (blk 0..127) + A/B tables (128..135) + C tables (136..139)
__global__ __launch_bounds__(1024) void k_prep(
    const float* __restrict__ query, const float* __restrict__ entity,
    const float* __restrict__ Wq, const float* __restrict__ bq,
    const float* __restrict__ Wk, const float* __restrict__ bk,
    const float* __restrict__ Wv, const float* __restrict__ We,
    const float* __restrict__ be, const float* __restrict__ Wa,
    const float* __restrict__ Wo, float* __restrict__ ws)
{
    __shared__ __align__(16) float red[16 * 512];   // 32 KB
    __shared__ __align__(16) float uo[516];
    int blk = blockIdx.x;
    int tid = threadIdx.x;

    if (blk < 128) {
        int o = blk * 1024 + tid;              // 0..131071
        const float4* src; float4* dst; int idx; int D;
        if (o < 32768)      { src = (const float4*)Wv; dst = (float4*)(ws + WTV); idx = o;         D = 256; }
        else if (o < 65536) { src = (const float4*)We; dst = (float4*)(ws + WTE); idx = o - 32768; D = 256; }
        else                { src = (const float4*)Wo; dst = (float4*)(ws + WTO); idx = o - 65536; D = 512; }
        int d  = idx >> 7;
        int k4 = idx & 127;
        dst[k4 * D + d] = src[idx];            // coalesced read, scattered write
        return;
    }

    int wv   = __builtin_amdgcn_readfirstlane(tid >> 6);
    int lane = tid & 63;

    if (blk < 136) {
        // A/B tables via u = W^T wa_slice (verified r7 body)
        int tab = blk - 128;                   // 0..7
        int p   = (tab < 4) ? tab : tab - 4;
        int b   = p >> 1, h = p & 1;
        const float* wa   = Wa + ((tab < 4) ? 0 : 256);
        const float* W    = h ? We : ((tab < 4) ? Wq : Wk);
        const float* bias = h ? be : ((tab < 4) ? bq : bk);
        const float* x    = h ? entity : query;

        float u8[8];
        #pragma unroll
        for (int i = 0; i < 8; i++) u8[i] = 0.f;
        #pragma unroll 4
        for (int dd = 0; dd < 16; dd++) {
            int d = wv * 16 + dd;
            float wad = wa[d];                                  // wave-uniform
            const float4* Wr = (const float4*)(W + (size_t)d * 512);
            float4 w0 = Wr[lane * 2], w1 = Wr[lane * 2 + 1];    // coalesced
            u8[0] += wad * w0.x; u8[1] += wad * w0.y; u8[2] += wad * w0.z; u8[3] += wad * w0.w;
            u8[4] += wad * w1.x; u8[5] += wad * w1.y; u8[6] += wad * w1.z; u8[7] += wad * w1.w;
        }
        #pragma unroll
        for (int i = 0; i < 8; i++) red[wv * 512 + lane * 8 + i] = u8[i];
        __syncthreads();
        if (tid < 512) {
            float s = 0.f;
            #pragma unroll
            for (int w = 0; w < 16; w++) s += red[w * 512 + tid];
            uo[tid] = s;
        }
        __syncthreads();
        if (tid < 256) red[tid] = wa[tid] * bias[tid];
        __syncthreads();
        for (int o = 128; o >= 1; o >>= 1) {
            if (tid < o) red[tid] += red[tid + o];
            __syncthreads();
        }
        float off = red[0];

        const float4* u4 = (const float4*)uo;
        float4 ua = u4[lane * 2], ub = u4[lane * 2 + 1];
        for (int rr = 0; rr < 12; rr++) {
            int r = wv * 12 + rr;
            const float4* xr = (const float4*)(x + (size_t)(r * 2 + b) * 512);
            float4 a0 = xr[lane * 2], a1 = xr[lane * 2 + 1];
            float pp = a0.x*ua.x + a0.y*ua.y + a0.z*ua.z + a0.w*ua.w
                     + a1.x*ub.x + a1.y*ub.y + a1.z*ub.z + a1.w*ub.w;
            pp = wave_reduce_add(pp);
            if (lane == 0) ws[TO + tab * SS + r] = pp + off;
        }
        return;
    }

    // C tables
    {
        int m = blk - 136;                     // 0..3
        float4 wa4 = ((const float4*)(Wa + 512))[lane];
        for (int rr = 0; rr < 12; rr++) {
            int i = wv * 12 + rr;
            const float4* er = (const float4*)(entity
                + (size_t)(i * 2 + (m >> 1)) * 512 + (m & 1) * 256);
            float4 e4 = er[lane];
            float pp = e4.x*wa4.x + e4.y*wa4.y + e4.z*wa4.z + e4.w*wa4.w;
            pp = wave_reduce_add(pp);
            if (lane == 0) ws[TO + (8 + m) * SS + i] = pp;
        }
    }
}

// ===== K2: v,e projections. 192 blocks x 1024 thr, 4 rows/block, split-k x4.
__global__ __launch_bounds__(1024) void k_proj(
    const float* __restrict__ query, const float* __restrict__ entity,
    const float* __restrict__ bv, const float* __restrict__ be,
    float* __restrict__ ws)
{
    __shared__ float lds[4096];
    int blk = blockIdx.x;
    int m  = blk / 96;                     // 0: v(query), 1: e(entity)
    int r0 = (blk % 96) * 4;
    int tid = threadIdx.x;
    int chunk = __builtin_amdgcn_readfirstlane(tid >> 8);
    int d  = tid & 255;
    const float*  A    = m ? entity : query;
    const float*  bias = m ? be : bv;
    const float4* WT   = (const float4*)(ws + (m ? WTE : WTV));
    float*        dst  = ws + (m ? EO : VO);
    const float4* A4   = (const float4*)A;   // [384][128]

    float acc[4];
    #pragma unroll
    for (int r = 0; r < 4; r++) acc[r] = 0.f;

    int k4b = chunk * 32;
    #pragma unroll 8
    for (int i = 0; i < 32; i++) {
        int k4 = k4b + i;
        float4 w = WT[k4 * 256 + d];
        #pragma unroll
        for (int r = 0; r < 4; r++) {
            float4 a = A4[(r0 + r) * 128 + k4];   // wave-uniform -> s_load
            acc[r] += a.x * w.x + a.y * w.y + a.z * w.z + a.w * w.w;
        }
    }
    #pragma unroll
    for (int r = 0; r < 4; r++) lds[(chunk * 4 + r) * 256 + d] = acc[r];
    __syncthreads();
    {
        int idx = tid;
        int rr  = idx >> 8, dd = idx & 255;
        float v = lds[idx] + lds[1024 + idx] + lds[2048 + idx] + lds[3072 + idx];
        dst[(size_t)(r0 + rr) * 256 + dd] = v + bias[dd];
    }
}

// ===== K3: attention + output fc. 96 blocks (b, tg) x 1024 thr.
__global__ __launch_bounds__(1024) void k_attnout(
    const float* __restrict__ ba_p, const float* __restrict__ bo,
    float* __restrict__ ws, float* __restrict__ out)
{
    __shared__ __align__(16) float spT[SS * 8];     // [s][h*4+ti]  6 KB
    __shared__ __align__(16) float partU[8192];     // 32 KB multi-use
    int blk = blockIdx.x;
    int b   = blk / 48;
    int tg  = blk % 48;                    // t = tg*4 + ti
    int tid  = threadIdx.x;
    int wvi  = __builtin_amdgcn_readfirstlane(tid >> 6);
    int lane = tid & 63;
    const float* T = ws + TO;
    float ba = ba_p[0];

    // --- softmax: waves 0..7 own (h = wvi>>2, ti = wvi&3)   [verified body]
    if (wvi < 8) {
        int h = wvi >> 2, ti = wvi & 3;
        int bh = 2 * b + h;
        int i_idx = bh * 48 + tg;
        float sc[3]; float mx = -1e30f;
        #pragma unroll
        for (int i = 0; i < 3; i++) {
            int s_ = lane + 64 * i;
            int m  = s_ & 3;
            int j  = ti * 48 + (s_ >> 2);
            float xv = T[m * SS + i_idx] + T[(4 + ti) * SS + s_]
                     + T[(8 + m) * SS + i_idx] - T[(8 + m) * SS + j] + ba;
            xv = (xv >= 0.f) ? xv : 0.01f * xv;      // leaky_relu
            sc[i] = xv; mx = fmaxf(mx, xv);
        }
        #pragma unroll
        for (int o = 32; o >= 1; o >>= 1) mx = fmaxf(mx, __shfl_xor(mx, o, 64));
        float sum = 0.f;
        #pragma unroll
        for (int i = 0; i < 3; i++) { sc[i] = __expf(sc[i] - mx); sum += sc[i]; }
        sum = wave_reduce_add(sum);
        float inv = 1.f / sum;
        #pragma unroll
        for (int i = 0; i < 3; i++)
            spT[(lane + 64 * i) * 8 + h * 4 + ti] = sc[i] * inv;
    }
    __syncthreads();

    // --- PV: thread (h = tid>>9, sq = (tid>>7)&3, d2 = tid&127), float2
    {
        int h  = __builtin_amdgcn_readfirstlane(tid >> 9);
        int sq = __builtin_amdgcn_readfirstlane((tid >> 7) & 3);
        int d2 = tid & 127;
        const float2* src2 = (const float2*)(ws + (h ? EO : VO));   // [384][128]
        const float4* spT4 = (const float4*)spT;
        float2 acc2[4];
        #pragma unroll
        for (int ti = 0; ti < 4; ti++) acc2[ti] = make_float2(0.f, 0.f);
        int s0 = sq * 48;
        #pragma unroll 8
        for (int s2 = 0; s2 < 48; s2++) {
            int s = s0 + s2;
            float4 p4 = spT4[s * 2 + h];          // one b128 broadcast: 4 ti weights
            float2 v  = src2[(size_t)(s * 2 + b) * 128 + d2];
            acc2[0].x += p4.x * v.x; acc2[0].y += p4.x * v.y;
            acc2[1].x += p4.y * v.x; acc2[1].y += p4.y * v.y;
            acc2[2].x += p4.z * v.x; acc2[2].y += p4.z * v.y;
            acc2[3].x += p4.w * v.x; acc2[3].y += p4.w * v.y;
        }
        float2* pf2 = (float2*)partU;             // [ (h*4+sq)*4+ti ][128]
        #pragma unroll
        for (int ti = 0; ti < 4; ti++)
            pf2[((h * 4 + sq) * 4 + ti) * 128 + d2] = acc2[ti];
    }
    __syncthreads();

    // --- reduce partials -> rows in GLOBAL ws (for scalar-cache GEMV reads)
    {
        const float* partf = partU;               // [(h*4+sq)*4+ti][256]
        int ti = tid >> 8, dd = tid & 255;
        float r0 = 0.f, r1 = 0.f;
        #pragma unroll
        for (int sq = 0; sq < 4; sq++) {
            r0 += partf[((0 + sq) * 4 + ti) * 256 + dd];
            r1 += partf[((4 + sq) * 4 + ti) * 256 + dd];
        }
        float* wsrows = ws + ROWS + blk * 2048;
        wsrows[ti * 512 + dd]       = r0;
        wsrows[ti * 512 + 256 + dd] = r1;
    }
    __syncthreads();                              // emits vmcnt(0) before barrier
    // scalar L1 may hold the PREVIOUS replay's rows lines — invalidate.
    asm volatile("s_dcache_inv" ::: "memory");

    // --- out GEMV (r9 k_out body): rows via wave-uniform s_load broadcasts
    {
        int kc = __builtin_amdgcn_readfirstlane(tid >> 8);   // split-k x4
        int cl = tid & 255;
        const float4* A4 = (const float4*)(ws + ROWS + blk * 2048);  // [4][128]
        const float4* WT = (const float4*)(ws + WTO);                // [128][512]
        float acc0[4], acc1[4];
        #pragma unroll
        for (int r = 0; r < 4; r++) { acc0[r] = 0.f; acc1[r] = 0.f; }
        int k4b = kc * 32;
        #pragma unroll 8
        for (int i = 0; i < 32; i++) {
            int k4 = k4b + i;
            float4 w0 = WT[k4 * 512 + cl];        // coalesced
            float4 w1 = WT[k4 * 512 + cl + 256];  // coalesced
            #pragma unroll
            for (int r = 0; r < 4; r++) {
                float4 a = A4[r * 128 + k4];      // uniform -> s_load (post-inv)
                acc0[r] += a.x * w0.x + a.y * w0.y + a.z * w0.z + a.w * w0.w;
                acc1[r] += a.x * w1.x + a.y * w1.y + a.z * w1.z + a.w * w1.w;
            }
        }
        #pragma unroll
        for (int r = 0; r < 4; r++) {
            partU[kc * 2048 + r * 512 + cl]       = acc0[r];
            partU[kc * 2048 + r * 512 + 256 + cl] = acc1[r];
        }
    }
    __syncthreads();
    // final reduce + store (2048 outputs, 2 per thread, coalesced)
    #pragma unroll
    for (int o = 0; o < 2; o++) {
        int idx = o * 1024 + tid;
        int ti = idx >> 9, c = idx & 511;
        float v = partU[ti * 512 + c] + partU[2048 + ti * 512 + c]
                + partU[4096 + ti * 512 + c] + partU[6144 + ti * 512 + c];
        int t = tg * 4 + ti;
        out[(size_t)(2 * t + b) * 512 + c] = v + bo[c];
    }
}

extern "C" void kernel_launch(void* const* d_in, const int* in_sizes, int n_in,
                              void* d_out, int out_size, void* d_ws, size_t ws_size,
                              hipStream_t stream) {
    const float* query  = (const float*)d_in[0];
    const float* entity = (const float*)d_in[1];
    // d_in[2] ex_entity, d_in[3] ex_relation: dead
    const float* Wq = (const float*)d_in[4];  const float* bq = (const float*)d_in[5];
    const float* Wk = (const float*)d_in[6];  const float* bk = (const float*)d_in[7];
    const float* Wv = (const float*)d_in[8];  const float* bv = (const float*)d_in[9];
    const float* We = (const float*)d_in[10]; const float* be = (const float*)d_in[11];
    // d_in[12..15] dead
    const float* Wa = (const float*)d_in[16]; const float* ba = (const float*)d_in[17];
    const float* Wo = (const float*)d_in[18]; const float* bo = (const float*)d_in[19];
    float* ws  = (float*)d_ws;
    float* out = (float*)d_out;

    hipLaunchKernelGGL(k_prep, dim3(140), dim3(1024), 0, stream,
                       query, entity, Wq, bq, Wk, bk, Wv, We, be, Wa, Wo, ws);
    hipLaunchKernelGGL(k_proj, dim3(192), dim3(1024), 0, stream,
                       query, entity, bv, be, ws);
    hipLaunchKernelGGL(k_attnout, dim3(96), dim3(1024), 0, stream,
                       ba, bo, ws, out);
}

// Round 13
// 68.673 us; speedup vs baseline: 1.1559x; 1.0025x over previous
//
#include <hip/hip_runtime.h>
#include <math.h>

// DecoderGATLayer — 3 flat kernels. f32. S=192, B=2, E=512, H=2, D=256, BH=4.
// Dead inputs: ex_entity, ex_relation, Wxe, Wxr (reference deletes `we`).
// score[bh,t,s] = A[s&3][i] + B[t&3][s] + C[s&3][i] - C[s&3][j] + ba,
//   i = bh*48 + (t>>2), j = (t&3)*48 + (s>>2)
// q/k projections folded into tables via u = W^T wa_slice (verified r7).
// K1 prep: transposes Wv/We/Wo + tables.  K2: v,e projections (s_load rows).
// K3: attn (softmax + PV) + out GEMV; rows staged in ws so the GEMV reads
//     them via scalar-cache broadcasts; s_dcache_inv guards replay staleness.

#define SS 192
// ws float offsets
#define WTV 0          // [128 k4][256 d] float4-over-k
#define WTE 131072
#define WTO 262144     // [128 k4][512 c] float4-over-k
#define TO  524288     // 12*192 tables
#define VO  526592     // [384][256], row = s*2+b
#define EO  624896
#define ROWS 723200    // per-block rows: [96 blk][4 ti][512]
// end 919808 floats = 3.5 MB

__device__ __forceinline__ float wave_reduce_add(float p) {
    #pragma unroll
    for (int off = 32; off >= 1; off >>= 1) p += __shfl_xor(p, off, 64);
    return p;
}

// ===== K1: transposes (blk 0..127) + A/B tables (128..135) + C tables (136..139)
__global__ __launch_bounds__(1024) void k_prep(
    const float* __restrict__ query, const float* __restrict__ entity,
    const float* __restrict__ Wq, const float* __restrict__ bq,
    const float* __restrict__ Wk, const float* __restrict__ bk,
    const float* __restrict__ Wv, const float* __restrict__ We,
    const float* __restrict__ be, const float* __restrict__ Wa,
    const float* __restrict__ Wo, float* __restrict__ ws)
{
    __shared__ __align__(16) float red[16 * 512];   // 32 KB
    __shared__ __align__(16) float uo[516];
    int blk = blockIdx.x;
    int tid = threadIdx.x;

    if (blk < 128) {
        int o = blk * 1024 + tid;              // 0..131071
        const float4* src; float4* dst; int idx; int D;
        if (o < 32768)      { src = (const float4*)Wv; dst = (float4*)(ws + WTV); idx = o;         D = 256; }
        else if (o < 65536) { src = (const float4*)We; dst = (float4*)(ws + WTE); idx = o - 32768; D = 256; }
        else                { src = (const float4*)Wo; dst = (float4*)(ws + WTO); idx = o - 65536; D = 512; }
        int d  = idx >> 7;
        int k4 = idx & 127;
        dst[k4 * D + d] = src[idx];            // coalesced read, scattered write
        return;
    }

    int wv   = __builtin_amdgcn_readfirstlane(tid >> 6);
    int lane = tid & 63;

    if (blk < 136) {
        // A/B tables via u = W^T wa_slice (verified r7 body)
        int tab = blk - 128;                   // 0..7
        int p   = (tab < 4) ? tab : tab - 4;
        int b   = p >> 1, h = p & 1;
        const float* wa   = Wa + ((tab < 4) ? 0 : 256);
        const float* W    = h ? We : ((tab < 4) ? Wq : Wk);
        const float* bias = h ? be : ((tab < 4) ? bq : bk);
        const float* x    = h ? entity : query;

        float u8[8];
        #pragma unroll
        for (int i = 0; i < 8; i++) u8[i] = 0.f;
        #pragma unroll 4
        for (int dd = 0; dd < 16; dd++) {
            int d = wv * 16 + dd;
            float wad = wa[d];                                  // wave-uniform
            const float4* Wr = (const float4*)(W + (size_t)d * 512);
            float4 w0 = Wr[lane * 2], w1 = Wr[lane * 2 + 1];    // coalesced
            u8[0] += wad * w0.x; u8[1] += wad * w0.y; u8[2] += wad * w0.z; u8[3] += wad * w0.w;
            u8[4] += wad * w1.x; u8[5] += wad * w1.y; u8[6] += wad * w1.z; u8[7] += wad * w1.w;
        }
        #pragma unroll
        for (int i = 0; i < 8; i++) red[wv * 512 + lane * 8 + i] = u8[i];
        __syncthreads();
        if (tid < 512) {
            float s = 0.f;
            #pragma unroll
            for (int w = 0; w < 16; w++) s += red[w * 512 + tid];
            uo[tid] = s;
        }
        __syncthreads();
        if (tid < 256) red[tid] = wa[tid] * bias[tid];
        __syncthreads();
        for (int o = 128; o >= 1; o >>= 1) {
            if (tid < o) red[tid] += red[tid + o];
            __syncthreads();
        }
        float off = red[0];

        const float4* u4 = (const float4*)uo;
        float4 ua = u4[lane * 2], ub = u4[lane * 2 + 1];
        for (int rr = 0; rr < 12; rr++) {
            int r = wv * 12 + rr;
            const float4* xr = (const float4*)(x + (size_t)(r * 2 + b) * 512);
            float4 a0 = xr[lane * 2], a1 = xr[lane * 2 + 1];
            float pp = a0.x*ua.x + a0.y*ua.y + a0.z*ua.z + a0.w*ua.w
                     + a1.x*ub.x + a1.y*ub.y + a1.z*ub.z + a1.w*ub.w;
            pp = wave_reduce_add(pp);
            if (lane == 0) ws[TO + tab * SS + r] = pp + off;
        }
        return;
    }

    // C tables
    {
        int m = blk - 136;                     // 0..3
        float4 wa4 = ((const float4*)(Wa + 512))[lane];
        for (int rr = 0; rr < 12; rr++) {
            int i = wv * 12 + rr;
            const float4* er = (const float4*)(entity
                + (size_t)(i * 2 + (m >> 1)) * 512 + (m & 1) * 256);
            float4 e4 = er[lane];
            float pp = e4.x*wa4.x + e4.y*wa4.y + e4.z*wa4.z + e4.w*wa4.w;
            pp = wave_reduce_add(pp);
            if (lane == 0) ws[TO + (8 + m) * SS + i] = pp;
        }
    }
}

// ===== K2: v,e projections. 192 blocks x 1024 thr, 4 rows/block, split-k x4.
__global__ __launch_bounds__(1024) void k_proj(
    const float* __restrict__ query, const float* __restrict__ entity,
    const float* __restrict__ bv, const float* __restrict__ be,
    float* __restrict__ ws)
{
    __shared__ float lds[4096];
    int blk = blockIdx.x;
    int m  = blk / 96;                     // 0: v(query), 1: e(entity)
    int r0 = (blk % 96) * 4;
    int tid = threadIdx.x;
    int chunk = __builtin_amdgcn_readfirstlane(tid >> 8);
    int d  = tid & 255;
    const float*  A    = m ? entity : query;
    const float*  bias = m ? be : bv;
    const float4* WT   = (const float4*)(ws + (m ? WTE : WTV));
    float*        dst  = ws + (m ? EO : VO);
    const float4* A4   = (const float4*)A;   // [384][128]

    float acc[4];
    #pragma unroll
    for (int r = 0; r < 4; r++) acc[r] = 0.f;

    int k4b = chunk * 32;
    #pragma unroll 8
    for (int i = 0; i < 32; i++) {
        int k4 = k4b + i;
        float4 w = WT[k4 * 256 + d];
        #pragma unroll
        for (int r = 0; r < 4; r++) {
            float4 a = A4[(r0 + r) * 128 + k4];   // wave-uniform -> s_load
            acc[r] += a.x * w.x + a.y * w.y + a.z * w.z + a.w * w.w;
        }
    }
    #pragma unroll
    for (int r = 0; r < 4; r++) lds[(chunk * 4 + r) * 256 + d] = acc[r];
    __syncthreads();
    {
        int idx = tid;
        int rr  = idx >> 8, dd = idx & 255;
        float v = lds[idx] + lds[1024 + idx] + lds[2048 + idx] + lds[3072 + idx];
        dst[(size_t)(r0 + rr) * 256 + dd] = v + bias[dd];
    }
}

// ===== K3: attention + output fc. 96 blocks (b, tg) x 1024 thr.
__global__ __launch_bounds__(1024) void k_attnout(
    const float* __restrict__ ba_p, const float* __restrict__ bo,
    float* __restrict__ ws, float* __restrict__ out)
{
    __shared__ __align__(16) float spT[SS * 8];     // [s][h*4+ti]  6 KB
    __shared__ __align__(16) float partU[8192];     // 32 KB multi-use
    int blk = blockIdx.x;
    int b   = blk / 48;
    int tg  = blk % 48;                    // t = tg*4 + ti
    int tid  = threadIdx.x;
    int wvi  = __builtin_amdgcn_readfirstlane(tid >> 6);
    int lane = tid & 63;
    const float* T = ws + TO;
    float ba = ba_p[0];

    // --- softmax: waves 0..7 own (h = wvi>>2, ti = wvi&3)   [verified body]
    if (wvi < 8) {
        int h = wvi >> 2, ti = wvi & 3;
        int bh = 2 * b + h;
        int i_idx = bh * 48 + tg;
        float sc[3]; float mx = -1e30f;
        #pragma unroll
        for (int i = 0; i < 3; i++) {
            int s_ = lane + 64 * i;
            int m  = s_ & 3;
            int j  = ti * 48 + (s_ >> 2);
            float xv = T[m * SS + i_idx] + T[(4 + ti) * SS + s_]
                     + T[(8 + m) * SS + i_idx] - T[(8 + m) * SS + j] + ba;
            xv = (xv >= 0.f) ? xv : 0.01f * xv;      // leaky_relu
            sc[i] = xv; mx = fmaxf(mx, xv);
        }
        #pragma unroll
        for (int o = 32; o >= 1; o >>= 1) mx = fmaxf(mx, __shfl_xor(mx, o, 64));
        float sum = 0.f;
        #pragma unroll
        for (int i = 0; i < 3; i++) { sc[i] = __expf(sc[i] - mx); sum += sc[i]; }
        sum = wave_reduce_add(sum);
        float inv = 1.f / sum;
        #pragma unroll
        for (int i = 0; i < 3; i++)
            spT[(lane + 64 * i) * 8 + h * 4 + ti] = sc[i] * inv;
    }
    __syncthreads();

    // --- PV: thread (h = tid>>9, sq = (tid>>7)&3, d2 = tid&127), float2
    {
        int h  = __builtin_amdgcn_readfirstlane(tid >> 9);
        int sq = __builtin_amdgcn_readfirstlane((tid >> 7) & 3);
        int d2 = tid & 127;
        const float2* src2 = (const float2*)(ws + (h ? EO : VO));   // [384][128]
        const float4* spT4 = (const float4*)spT;
        float2 acc2[4];
        #pragma unroll
        for (int ti = 0; ti < 4; ti++) acc2[ti] = make_float2(0.f, 0.f);
        int s0 = sq * 48;
        #pragma unroll 8
        for (int s2 = 0; s2 < 48; s2++) {
            int s = s0 + s2;
            float4 p4 = spT4[s * 2 + h];          // one b128 broadcast: 4 ti weights
            float2 v  = src2[(size_t)(s * 2 + b) * 128 + d2];
            acc2[0].x += p4.x * v.x; acc2[0].y += p4.x * v.y;
            acc2[1].x += p4.y * v.x; acc2[1].y += p4.y * v.y;
            acc2[2].x += p4.z * v.x; acc2[2].y += p4.z * v.y;
            acc2[3].x += p4.w * v.x; acc2[3].y += p4.w * v.y;
        }
        float2* pf2 = (float2*)partU;             // [ (h*4+sq)*4+ti ][128]
        #pragma unroll
        for (int ti = 0; ti < 4; ti++)
            pf2[((h * 4 + sq) * 4 + ti) * 128 + d2] = acc2[ti];
    }
    __syncthreads();

    // --- reduce partials -> rows in GLOBAL ws (for scalar-cache GEMV reads)
    {
        const float* partf = partU;               // [(h*4+sq)*4+ti][256]
        int ti = tid >> 8, dd = tid & 255;
        float r0 = 0.f, r1 = 0.f;
        #pragma unroll
        for (int sq = 0; sq < 4; sq++) {
            r0 += partf[((0 + sq) * 4 + ti) * 256 + dd];
            r1 += partf[((4 + sq) * 4 + ti) * 256 + dd];
        }
        float* wsrows = ws + ROWS + blk * 2048;
        wsrows[ti * 512 + dd]       = r0;
        wsrows[ti * 512 + 256 + dd] = r1;
    }
    __syncthreads();                              // emits vmcnt(0) before barrier
    // scalar L1 may hold the PREVIOUS replay's rows lines — invalidate.
    asm volatile("s_dcache_inv" ::: "memory");

    // --- out GEMV (r9 k_out body): rows via wave-uniform s_load broadcasts
    {
        int kc = __builtin_amdgcn_readfirstlane(tid >> 8);   // split-k x4
        int cl = tid & 255;
        const float4* A4 = (const float4*)(ws + ROWS + blk * 2048);  // [4][128]
        const float4* WT = (const float4*)(ws + WTO);                // [128][512]
        float acc0[4], acc1[4];
        #pragma unroll
        for (int r = 0; r < 4; r++) { acc0[r] = 0.f; acc1[r] = 0.f; }
        int k4b = kc * 32;
        #pragma unroll 8
        for (int i = 0; i < 32; i++) {
            int k4 = k4b + i;
            float4 w0 = WT[k4 * 512 + cl];        // coalesced
            float4 w1 = WT[k4 * 512 + cl + 256];  // coalesced
            #pragma unroll
            for (int r = 0; r < 4; r++) {
                float4 a = A4[r * 128 + k4];      // uniform -> s_load (post-inv)
                acc0[r] += a.x * w0.x + a.y * w0.y + a.z * w0.z + a.w * w0.w;
                acc1[r] += a.x * w1.x + a.y * w1.y + a.z * w1.z + a.w * w1.w;
            }
        }
        #pragma unroll
        for (int r = 0; r < 4; r++) {
            partU[kc * 2048 + r * 512 + cl]       = acc0[r];
            partU[kc * 2048 + r * 512 + 256 + cl] = acc1[r];
        }
    }
    __syncthreads();
    // final reduce + store (2048 outputs, 2 per thread, coalesced)
    #pragma unroll
    for (int o = 0; o < 2; o++) {
        int idx = o * 1024 + tid;
        int ti = idx >> 9, c = idx & 511;
        float v = partU[ti * 512 + c] + partU[2048 + ti * 512 + c]
                + partU[4096 + ti * 512 + c] + partU[6144 + ti * 512 + c];
        int t = tg * 4 + ti;
        out[(size_t)(2 * t + b) * 512 + c] = v + bo[c];
    }
}

extern "C" void kernel_launch(void* const* d_in, const int* in_sizes, int n_in,
                              void* d_out, int out_size, void* d_ws, size_t ws_size,
                              hipStream_t stream) {
    const float* query  = (const float*)d_in[0];
    const float* entity = (const float*)d_in[1];
    // d_in[2] ex_entity, d_in[3] ex_relation: dead
    const float* Wq = (const float*)d_in[4];  const float* bq = (const float*)d_in[5];
    const float* Wk = (const float*)d_in[6];  const float* bk = (const float*)d_in[7];
    const float* Wv = (const float*)d_in[8];  const float* bv = (const float*)d_in[9];
    const float* We = (const float*)d_in[10]; const float* be = (const float*)d_in[11];
    // d_in[12..15] dead
    const float* Wa = (const float*)d_in[16]; const float* ba = (const float*)d_in[17];
    const float* Wo = (const float*)d_in[18]; const float* bo = (const float*)d_in[19];
    float* ws  = (float*)d_ws;
    float* out = (float*)d_out;

    hipLaunchKernelGGL(k_prep, dim3(140), dim3(1024), 0, stream,
                       query, entity, Wq, bq, Wk, bk, Wv, We, be, Wa, Wo, ws);
    hipLaunchKernelGGL(k_proj, dim3(192), dim3(1024), 0, stream,
                       query, entity, bv, be, ws);
    hipLaunchKernelGGL(k_attnout, dim3(96), dim3(1024), 0, stream,
                       ba, bo, ws, out);
}

// Round 14
// 58.334 us; speedup vs baseline: 1.3607x; 1.1772x over previous
//
#include <hip/hip_runtime.h>
#include <math.h>

// DecoderGATLayer — memset + 3 flat kernels. f32. S=192,B=2,E=512,H=2,D=256,BH=4.
// Dead inputs: ex_entity, ex_relation, Wxe, Wxr (reference deletes `we`).
// score[bh,t,s] = A[s&3][i] + B[t&3][s] + C[s&3][i] - C[s&3][j] + ba,
//   i = bh*48 + (t>>2), j = (t&3)*48 + (s>>2)
// q/k projections folded into tables via u = W^T wa_slice (verified r7).
// K1 prep: transposes Wv/We/Wo + tables.
// K2 proj: v,e projections; 192 blocks read WT *quarters* (256KB each).
// K3 attn+out: block=(b,tg,h): softmax+PV(head h) -> rows via ws (s_load +
//   s_dcache_inv, r13-proven) -> GEMV over k-half of WTO -> atomicAdd to out.

#define SS 192
// ws float offsets
#define WTV 0          // [128 k4][256 d] float4-over-k
#define WTE 131072
#define WTO 262144     // [128 k4][512 c] float4-over-k
#define TO  524288     // 12*192 tables
#define VO  526592     // [384][256], row = s*2+b
#define EO  624896
#define ROWS 723200    // per-block rows: [192 blk][4 ti][256]
// end 919808 floats = 3.5 MB

__device__ __forceinline__ float wave_reduce_add(float p) {
    #pragma unroll
    for (int off = 32; off >= 1; off >>= 1) p += __shfl_xor(p, off, 64);
    return p;
}

// ===== K1: transposes (blk 0..127) + A/B tables (128..135) + C tables (136..139)
__global__ __launch_bounds__(1024) void k_prep(
    const float* __restrict__ query, const float* __restrict__ entity,
    const float* __restrict__ Wq, const float* __restrict__ bq,
    const float* __restrict__ Wk, const float* __restrict__ bk,
    const float* __restrict__ Wv, const float* __restrict__ We,
    const float* __restrict__ be, const float* __restrict__ Wa,
    const float* __restrict__ Wo, float* __restrict__ ws)
{
    __shared__ __align__(16) float red[16 * 512];   // 32 KB
    __shared__ __align__(16) float uo[516];
    int blk = blockIdx.x;
    int tid = threadIdx.x;

    if (blk < 128) {
        int o = blk * 1024 + tid;              // 0..131071
        const float4* src; float4* dst; int idx; int D;
        if (o < 32768)      { src = (const float4*)Wv; dst = (float4*)(ws + WTV); idx = o;         D = 256; }
        else if (o < 65536) { src = (const float4*)We; dst = (float4*)(ws + WTE); idx = o - 32768; D = 256; }
        else                { src = (const float4*)Wo; dst = (float4*)(ws + WTO); idx = o - 65536; D = 512; }
        int d  = idx >> 7;
        int k4 = idx & 127;
        dst[k4 * D + d] = src[idx];            // coalesced read, scattered write
        return;
    }

    int wv   = __builtin_amdgcn_readfirstlane(tid >> 6);
    int lane = tid & 63;

    if (blk < 136) {
        // A/B tables via u = W^T wa_slice (verified r7 body)
        int tab = blk - 128;                   // 0..7
        int p   = (tab < 4) ? tab : tab - 4;
        int b   = p >> 1, h = p & 1;
        const float* wa   = Wa + ((tab < 4) ? 0 : 256);
        const float* W    = h ? We : ((tab < 4) ? Wq : Wk);
        const float* bias = h ? be : ((tab < 4) ? bq : bk);
        const float* x    = h ? entity : query;

        float u8[8];
        #pragma unroll
        for (int i = 0; i < 8; i++) u8[i] = 0.f;
        #pragma unroll 4
        for (int dd = 0; dd < 16; dd++) {
            int d = wv * 16 + dd;
            float wad = wa[d];                                  // wave-uniform
            const float4* Wr = (const float4*)(W + (size_t)d * 512);
            float4 w0 = Wr[lane * 2], w1 = Wr[lane * 2 + 1];    // coalesced
            u8[0] += wad * w0.x; u8[1] += wad * w0.y; u8[2] += wad * w0.z; u8[3] += wad * w0.w;
            u8[4] += wad * w1.x; u8[5] += wad * w1.y; u8[6] += wad * w1.z; u8[7] += wad * w1.w;
        }
        #pragma unroll
        for (int i = 0; i < 8; i++) red[wv * 512 + lane * 8 + i] = u8[i];
        __syncthreads();
        if (tid < 512) {
            float s = 0.f;
            #pragma unroll
            for (int w = 0; w < 16; w++) s += red[w * 512 + tid];
            uo[tid] = s;
        }
        __syncthreads();
        if (tid < 256) red[tid] = wa[tid] * bias[tid];
        __syncthreads();
        for (int o = 128; o >= 1; o >>= 1) {
            if (tid < o) red[tid] += red[tid + o];
            __syncthreads();
        }
        float off = red[0];

        const float4* u4 = (const float4*)uo;
        float4 ua = u4[lane * 2], ub = u4[lane * 2 + 1];
        for (int rr = 0; rr < 12; rr++) {
            int r = wv * 12 + rr;
            const float4* xr = (const float4*)(x + (size_t)(r * 2 + b) * 512);
            float4 a0 = xr[lane * 2], a1 = xr[lane * 2 + 1];
            float pp = a0.x*ua.x + a0.y*ua.y + a0.z*ua.z + a0.w*ua.w
                     + a1.x*ub.x + a1.y*ub.y + a1.z*ub.z + a1.w*ub.w;
            pp = wave_reduce_add(pp);
            if (lane == 0) ws[TO + tab * SS + r] = pp + off;
        }
        return;
    }

    // C tables
    {
        int m = blk - 136;                     // 0..3
        float4 wa4 = ((const float4*)(Wa + 512))[lane];
        for (int rr = 0; rr < 12; rr++) {
            int i = wv * 12 + rr;
            const float4* er = (const float4*)(entity
                + (size_t)(i * 2 + (m >> 1)) * 512 + (m & 1) * 256);
            float4 e4 = er[lane];
            float pp = e4.x*wa4.x + e4.y*wa4.y + e4.z*wa4.z + e4.w*wa4.w;
            pp = wave_reduce_add(pp);
            if (lane == 0) ws[TO + (8 + m) * SS + i] = pp;
        }
    }
}

// ===== K2: v,e projections. 192 blocks = (m:2, dh:2, rg:48); 8 rows x 128 cols.
// thread (ks = tid>>7 [8 chunks of 16 k4], dl = tid&127). WT quarter = 256KB/blk.
__global__ __launch_bounds__(1024) void k_proj(
    const float* __restrict__ query, const float* __restrict__ entity,
    const float* __restrict__ bv, const float* __restrict__ be,
    float* __restrict__ ws)
{
    __shared__ float pl[8192];                 // [8 ks][8 r][128 dl] 32 KB
    int blk = blockIdx.x;
    int m   = blk / 96;                        // 0: v(query), 1: e(entity)
    int rem = blk % 96;
    int dh  = rem / 48;
    int rg  = rem % 48;
    int r0  = rg * 8;
    int d0  = dh * 128;
    int tid = threadIdx.x;
    int ks  = __builtin_amdgcn_readfirstlane(tid >> 7);
    int dl  = tid & 127;
    const float*  A    = m ? entity : query;
    const float*  bias = m ? be : bv;
    const float4* WT   = (const float4*)(ws + (m ? WTE : WTV));
    float*        dst  = ws + (m ? EO : VO);
    const float4* A4   = (const float4*)A;     // [384][128]

    float acc[8];
    #pragma unroll
    for (int r = 0; r < 8; r++) acc[r] = 0.f;

    int k4b = ks * 16;
    #pragma unroll 8
    for (int i = 0; i < 16; i++) {
        int k4 = k4b + i;
        float4 w = WT[k4 * 256 + d0 + dl];     // coalesced 128-wide
        #pragma unroll
        for (int r = 0; r < 8; r++) {
            float4 a = A4[(r0 + r) * 128 + k4];    // wave-uniform -> s_load
            acc[r] += a.x * w.x + a.y * w.y + a.z * w.z + a.w * w.w;
        }
    }
    #pragma unroll
    for (int r = 0; r < 8; r++) pl[ks * 1024 + r * 128 + dl] = acc[r];
    __syncthreads();
    {
        int r = tid >> 7, d2 = tid & 127;      // 1024 outputs, 1 each
        float v = 0.f;
        #pragma unroll
        for (int k = 0; k < 8; k++) v += pl[k * 1024 + r * 128 + d2];
        dst[(size_t)(r0 + r) * 256 + d0 + d2] = v + bias[d0 + d2];
    }
}

// ===== K3: attn + out. 192 blocks = (b, tg, h). atomicAdd into pre-zeroed out.
__global__ __launch_bounds__(1024) void k_attnout(
    const float* __restrict__ ba_p, const float* __restrict__ bo,
    float* __restrict__ ws, float* __restrict__ out)
{
    __shared__ __align__(16) float spT[SS * 4];     // [s][ti]  3 KB
    __shared__ __align__(16) float pu[8192];        // 32 KB multi-use
    int blk = blockIdx.x;
    int b   = blk / 96;
    int rem = blk % 96;
    int tg  = rem >> 1;                    // t = tg*4 + ti
    int h   = rem & 1;
    int tid  = threadIdx.x;
    int wvi  = __builtin_amdgcn_readfirstlane(tid >> 6);
    int lane = tid & 63;
    const float* T = ws + TO;
    float ba = ba_p[0];

    // --- softmax: waves 0..3 own ti   [verified body]
    if (wvi < 4) {
        int ti = wvi;
        int bh = 2 * b + h;
        int i_idx = bh * 48 + tg;
        float sc[3]; float mx = -1e30f;
        #pragma unroll
        for (int i = 0; i < 3; i++) {
            int s_ = lane + 64 * i;
            int m  = s_ & 3;
            int j  = ti * 48 + (s_ >> 2);
            float xv = T[m * SS + i_idx] + T[(4 + ti) * SS + s_]
                     + T[(8 + m) * SS + i_idx] - T[(8 + m) * SS + j] + ba;
            xv = (xv >= 0.f) ? xv : 0.01f * xv;      // leaky_relu
            sc[i] = xv; mx = fmaxf(mx, xv);
        }
        #pragma unroll
        for (int o = 32; o >= 1; o >>= 1) mx = fmaxf(mx, __shfl_xor(mx, o, 64));
        float sum = 0.f;
        #pragma unroll
        for (int i = 0; i < 3; i++) { sc[i] = __expf(sc[i] - mx); sum += sc[i]; }
        sum = wave_reduce_add(sum);
        float inv = 1.f / sum;
        #pragma unroll
        for (int i = 0; i < 3; i++)
            spT[(lane + 64 * i) * 4 + ti] = sc[i] * inv;
    }
    __syncthreads();

    // --- PV (head h): thread (sq = tid>>7 [8], d2 = tid&127), float2, 24 s each
    {
        int sq = __builtin_amdgcn_readfirstlane(tid >> 7);
        int d2 = tid & 127;
        const float2* src2 = (const float2*)(ws + (h ? EO : VO));   // [384][128]
        const float4* spT4 = (const float4*)spT;
        float2 acc2[4];
        #pragma unroll
        for (int ti = 0; ti < 4; ti++) acc2[ti] = make_float2(0.f, 0.f);
        int s0 = sq * 24;
        #pragma unroll 8
        for (int s2 = 0; s2 < 24; s2++) {
            int s = s0 + s2;
            float4 p4 = spT4[s];              // one b128 broadcast: 4 ti weights
            float2 v  = src2[(size_t)(s * 2 + b) * 128 + d2];
            acc2[0].x += p4.x * v.x; acc2[0].y += p4.x * v.y;
            acc2[1].x += p4.y * v.x; acc2[1].y += p4.y * v.y;
            acc2[2].x += p4.z * v.x; acc2[2].y += p4.z * v.y;
            acc2[3].x += p4.w * v.x; acc2[3].y += p4.w * v.y;
        }
        float2* pf2 = (float2*)pu;            // [sq][ti][128 f2]
        #pragma unroll
        for (int ti = 0; ti < 4; ti++)
            pf2[(sq * 4 + ti) * 128 + d2] = acc2[ti];
    }
    __syncthreads();

    // --- reduce partials -> rows (4x256) in GLOBAL ws for s_load GEMV reads
    {
        int ti = tid >> 8, dd = tid & 255;    // 1024 outputs, 1 each
        float v = 0.f;
        #pragma unroll
        for (int sq = 0; sq < 8; sq++) v += pu[(sq * 4 + ti) * 256 + dd];
        float* wsrows = ws + ROWS + blk * 1024;
        wsrows[ti * 256 + dd] = v;
    }
    __syncthreads();                          // drains vmcnt before barrier
    asm volatile("s_dcache_inv" ::: "memory");  // r13-proven replay-staleness guard

    // --- GEMV over k-half h: thread (kc = tid>>8, cl = tid&255)
    {
        int kc = __builtin_amdgcn_readfirstlane(tid >> 8);
        int cl = tid & 255;
        const float4* rows4 = (const float4*)(ws + ROWS + blk * 1024);  // [4][64]
        const float4* WTO4  = (const float4*)(ws + WTO);                // [128][512]
        float acc0[4], acc1[4];
        #pragma unroll
        for (int r = 0; r < 4; r++) { acc0[r] = 0.f; acc1[r] = 0.f; }
        int k4b = kc * 16;
        #pragma unroll 8
        for (int i = 0; i < 16; i++) {
            int k4l = k4b + i;                // 0..63 local
            int k4  = h * 64 + k4l;
            float4 w0 = WTO4[(size_t)k4 * 512 + cl];         // coalesced
            float4 w1 = WTO4[(size_t)k4 * 512 + cl + 256];   // coalesced
            #pragma unroll
            for (int r = 0; r < 4; r++) {
                float4 a = rows4[r * 64 + k4l];   // uniform -> s_load (post-inv)
                acc0[r] += a.x * w0.x + a.y * w0.y + a.z * w0.z + a.w * w0.w;
                acc1[r] += a.x * w1.x + a.y * w1.y + a.z * w1.z + a.w * w1.w;
            }
        }
        #pragma unroll
        for (int r = 0; r < 4; r++) {
            pu[kc * 2048 + r * 512 + cl]       = acc0[r];
            pu[kc * 2048 + r * 512 + 256 + cl] = acc1[r];
        }
    }
    __syncthreads();
    // --- final reduce + atomicAdd (2048 outputs, 2 per thread; h==0 adds bias)
    #pragma unroll
    for (int o = 0; o < 2; o++) {
        int idx = o * 1024 + tid;
        int ti = idx >> 9, c = idx & 511;
        float v = pu[ti * 512 + c] + pu[2048 + ti * 512 + c]
                + pu[4096 + ti * 512 + c] + pu[6144 + ti * 512 + c];
        if (h == 0) v += bo[c];
        int t = tg * 4 + ti;
        atomicAdd(&out[(size_t)(2 * t + b) * 512 + c], v);
    }
}

extern "C" void kernel_launch(void* const* d_in, const int* in_sizes, int n_in,
                              void* d_out, int out_size, void* d_ws, size_t ws_size,
                              hipStream_t stream) {
    const float* query  = (const float*)d_in[0];
    const float* entity = (const float*)d_in[1];
    // d_in[2] ex_entity, d_in[3] ex_relation: dead
    const float* Wq = (const float*)d_in[4];  const float* bq = (const float*)d_in[5];
    const float* Wk = (const float*)d_in[6];  const float* bk = (const float*)d_in[7];
    const float* Wv = (const float*)d_in[8];  const float* bv = (const float*)d_in[9];
    const float* We = (const float*)d_in[10]; const float* be = (const float*)d_in[11];
    // d_in[12..15] dead
    const float* Wa = (const float*)d_in[16]; const float* ba = (const float*)d_in[17];
    const float* Wo = (const float*)d_in[18]; const float* bo = (const float*)d_in[19];
    float* ws  = (float*)d_ws;
    float* out = (float*)d_out;

    hipMemsetAsync(out, 0, (size_t)out_size * sizeof(float), stream);
    hipLaunchKernelGGL(k_prep, dim3(140), dim3(1024), 0, stream,
                       query, entity, Wq, bq, Wk, bk, Wv, We, be, Wa, Wo, ws);
    hipLaunchKernelGGL(k_proj, dim3(192), dim3(1024), 0, stream,
                       query, entity, bv, be, ws);
    hipLaunchKernelGGL(k_attnout, dim3(192), dim3(1024), 0, stream,
                       ba, bo, ws, out);
}